// Round 2
// baseline (81.508 us; speedup 1.0000x reference)
//
#include <hip/hip_runtime.h>

#define NB 256
#define NS 2048
#define NP 64
#define ND 80
#define STILE 64
#define NTILE 32            // NS/STILE
#define NTHREADS 512

typedef __attribute__((ext_vector_type(4))) float f32x4;
typedef __attribute__((ext_vector_type(8))) short bf16x8;
typedef __attribute__((ext_vector_type(4))) short s16x4;
typedef unsigned short u16;

// ---------------- LDS layout (bytes) ----------------
// loop region (double buffered):
//   eh  : u16 [2][64][104]  @ 0       (26624)   bf16-hi of enc, [s][d], d padded 96 (zeros 80..95)
//   el  : u16 [2][64][104]  @ 26624   (26624)   bf16-lo residual
//   ehT : u16 [2][80][72]   @ 53248   (23040)   bf16-hi transposed [d][s], XOR-swizzled
//   mask: int [2][64]       @ 76288   (512)
// persistent:
//   mst : f32 [4][64] @ 76800 ; lst : f32 [4][64] @ 77824 ; mode: int @ 78848
// prologue overlay: W f32[80][84]@0 ; dec f32[64][84]@26880 ; qtmp f32[64][100]@0
// epilogue overlay: cacc f32[64][84]@0
#define SMEM_BYTES 82944    // >80KB forces exactly 1 block/CU

__device__ __forceinline__ unsigned pack2(float lo, float hi) {  // truncating
  return (__float_as_uint(lo) >> 16) | (__float_as_uint(hi) & 0xFFFF0000u);
}
__device__ __forceinline__ float bft(float f) {  // truncate to bf16-representable
  return __uint_as_float(__float_as_uint(f) & 0xFFFF0000u);
}
__device__ __forceinline__ u16 h16(float f) { return (u16)(__float_as_uint(f) >> 16); }
__device__ __forceinline__ u16 h16r(float f) {  // round-to-nearest-even bf16
  unsigned u = __float_as_uint(f);
  u += 0x7FFFu + ((u >> 16) & 1u);
  return (u16)(u >> 16);
}
__device__ __forceinline__ unsigned pack2r(float lo, float hi) {
  return (unsigned)h16r(lo) | ((unsigned)h16r(hi) << 16);
}

// D = A*B + C, 16x16, K=32 bf16. Guide-verified C/D: col=lane&15, row=4*(lane>>4)+r.
// A: m=lane&15, k-slots = 8 per lane-group; B: n=lane&15, same k-slot map (symmetric),
// so placing logical k identically on both sides is layout-robust.
__device__ __forceinline__ f32x4 mfma32(bf16x8 a, bf16x8 b, f32x4 c) {
  return __builtin_amdgcn_mfma_f32_16x16x32_bf16(a, b, c, 0, 0, 0);
}

__global__ __launch_bounds__(NTHREADS, 2)
void DecoderAttention_62989990363717_kernel(const float* __restrict__ enc,
                                            const float* __restrict__ dec,
                                            const int* __restrict__ maskp,
                                            const float* __restrict__ W,
                                            float* __restrict__ out)
{
  __shared__ __align__(16) char smem[SMEM_BYTES];

  u16* eh   = (u16*)smem;                 // [2][64][104]
  u16* el   = (u16*)(smem + 26624);
  u16* ehT  = (u16*)(smem + 53248);       // [2][80][72]
  int* mlds = (int*)(smem + 76288);       // [2][64]
  float* mst = (float*)(smem + 76800);    // [4][64]
  float* lst = (float*)(smem + 77824);    // [4][64]
  int* modep = (int*)(smem + 78848);

  const int tid  = (int)threadIdx.x;
  const int lane = tid & 63;
  const int wv   = tid >> 6;
  const int mp   = wv & 1;      // p-half: rows [32*mp, 32*mp+32)
  const int hq   = wv >> 1;     // s-quarter within tile: cols [16*hq, 16*hq+16)
  const int l15  = lane & 15;
  const int g    = lane >> 4;
  const int b    = (int)blockIdx.x;

  const float* encB = enc + (size_t)b * NS * ND;
  const float* decB = dec + (size_t)b * NP * ND;

  // ---------- prologue: W, dec -> LDS; mask-mode detect ----------
  {
    float* Wl = (float*)smem;            // [80][84]
    float* dl = (float*)(smem + 26880);  // [64][84]
    for (int i = tid; i < 80 * 80; i += NTHREADS) Wl[(i / 80) * 84 + (i % 80)] = W[i];
    for (int i = tid; i < 64 * 80; i += NTHREADS) dl[(i / 80) * 84 + (i % 80)] = decB[i];
    if (tid == 0) {
      const unsigned* mw = (const unsigned*)maskp;
      int ok = 1;
      for (int i = 0; i < 16; ++i) ok &= (mw[i] <= 1u);
      *modep = ok;   // 1 => int32 mask, 0 => int8 mask
    }
    __syncthreads();
    // Q = dec @ W^T in fp32 (thread: p = tid&63, e-chunk = tid>>6)
    const int qp = tid & 63, qw = tid >> 6;
    float qa[10];
#pragma unroll
    for (int j = 0; j < 10; ++j) qa[j] = 0.f;
    for (int kg = 0; kg < 20; ++kg) {
      f32x4 dv = *(const f32x4*)&dl[qp * 84 + kg * 4];
#pragma unroll
      for (int j = 0; j < 10; ++j) {
        f32x4 wvv = *(const f32x4*)&Wl[(qw * 10 + j) * 84 + kg * 4];
        qa[j] = fmaf(dv.x, wvv.x, qa[j]);
        qa[j] = fmaf(dv.y, wvv.y, qa[j]);
        qa[j] = fmaf(dv.z, wvv.z, qa[j]);
        qa[j] = fmaf(dv.w, wvv.w, qa[j]);
      }
    }
    __syncthreads();            // done reading W region
    float* qtmp = (float*)smem; // [64][100], zeros at d=80..95
#pragma unroll
    for (int j = 0; j < 10; ++j) qtmp[qp * 100 + qw * 10 + j] = qa[j];
    if (qw == 7) {
#pragma unroll
      for (int z = 0; z < 16; ++z) qtmp[qp * 100 + 80 + z] = 0.f;
    }
    __syncthreads();
  }

  // ---------- Q fragments (persistent, bf16 hi/lo split) ----------
  bf16x8 qb[2][3], qlb[2][3];
  {
    const float* qtmp = (const float*)smem;
#pragma unroll
    for (int nt = 0; nt < 2; ++nt) {
      const int prow = (2 * mp + nt) * 16 + l15;
#pragma unroll
      for (int kk = 0; kk < 3; ++kk) {
        const int d0 = kk * 32 + g * 8;
        f32x4 f0 = *(const f32x4*)&qtmp[prow * 100 + d0];
        f32x4 f1 = *(const f32x4*)&qtmp[prow * 100 + d0 + 4];
        float fv[8] = {f0.x, f0.y, f0.z, f0.w, f1.x, f1.y, f1.z, f1.w};
        union { u16 u[8]; bf16x8 v; } H, L;
#pragma unroll
        for (int j = 0; j < 8; ++j) {
          H.u[j] = h16(fv[j]);
          float rest = fv[j] - bft(fv[j]);
          L.u[j] = h16(rest);
        }
        qb[nt][kk] = H.v; qlb[nt][kk] = L.v;
      }
    }
  }
  __syncthreads();   // qtmp dead; staging may overwrite

  const int m32m = *modep;

  // loader roles: tid<256 stage enc (4 threads/row, 20 f32 each); wave4 stages mask
  const bool ldr = (tid < 256);
  const int lrow = (tid & 255) >> 2;
  const int lc   = tid & 3;
  const int ld0  = lc * 20;

#define STAGE_WRITE(bi)                                                          \
  do {                                                                           \
    if (ldr) {                                                                   \
      u16* ehB = eh + (bi) * 6656 + lrow * 104;                                  \
      u16* elB = el + (bi) * 6656 + lrow * 104;                                  \
      float fv[20];                                                              \
      _Pragma("unroll")                                                          \
      for (int q = 0; q < 5; ++q) {                                              \
        fv[4*q+0] = r[q].x; fv[4*q+1] = r[q].y; fv[4*q+2] = r[q].z; fv[4*q+3] = r[q].w; \
      }                                                                          \
      _Pragma("unroll")                                                          \
      for (int q = 0; q < 5; ++q) {                                              \
        float a0 = fv[4*q], a1 = fv[4*q+1], a2 = fv[4*q+2], a3 = fv[4*q+3];      \
        uint2 he; he.x = pack2(a0, a1); he.y = pack2(a2, a3);                    \
        *(uint2*)&ehB[ld0 + 4*q] = he;                                           \
        float c0 = a0 - bft(a0), c1 = a1 - bft(a1), c2 = a2 - bft(a2), c3 = a3 - bft(a3); \
        uint2 le; le.x = pack2(c0, c1); le.y = pack2(c2, c3);                    \
        *(uint2*)&elB[ld0 + 4*q] = le;                                           \
      }                                                                          \
      if (lc == 3) {  /* zero FULL K-pad 80..95 (16 u16 = 32 B) */               \
        uint4 z = make_uint4(0u, 0u, 0u, 0u);                                    \
        *(uint4*)&ehB[80] = z; *(uint4*)&ehB[88] = z;                            \
        *(uint4*)&elB[80] = z; *(uint4*)&elB[88] = z;                            \
      }                                                                          \
      u16* eT = ehT + (bi) * 5760;                                               \
      const int s4 = lrow >> 2, s3 = lrow & 3;                                   \
      _Pragma("unroll")                                                          \
      for (int i = 0; i < 20; ++i) {                                             \
        const int dd = ld0 + i;                                                  \
        eT[dd * 72 + ((s4 ^ (dd & 15)) << 2) + s3] = h16r(fv[i]);                \
      }                                                                          \
    }                                                                            \
    if (m32m) {                                                                  \
      if (tid >= 256 && tid < 320) mlds[(bi) * 64 + (tid - 256)] = ma;           \
    } else if (tid >= 256 && tid < 272) {                                        \
      int4 mm = make_int4((int)(mb & 0xFFu), (int)((mb >> 8) & 0xFFu),           \
                          (int)((mb >> 16) & 0xFFu), (int)(mb >> 24));           \
      *(int4*)&mlds[(bi) * 64 + 4 * (tid - 256)] = mm;                           \
    }                                                                            \
  } while (0)

  // ---------- stage tile 0 ----------
  {
    f32x4 r[5]; int ma = 0; unsigned mb = 0;
    if (ldr) {
      const float* src = encB + (size_t)lrow * ND + ld0;
#pragma unroll
      for (int q = 0; q < 5; ++q) r[q] = *(const f32x4*)(src + 4 * q);
    }
    if (m32m) { if (tid >= 256 && tid < 320) ma = maskp[(size_t)b * NS + (tid - 256)]; }
    else      { if (tid >= 256 && tid < 272) mb = ((const unsigned*)maskp)[(((size_t)b * NS) >> 2) + (tid - 256)]; }
    STAGE_WRITE(0);
    __syncthreads();
  }

  // ---------- main loop ----------
  f32x4 ctx0[5], ctx1[5];
#pragma unroll
  for (int n = 0; n < 5; ++n) { ctx0[n] = (f32x4){0.f,0.f,0.f,0.f}; ctx1[n] = (f32x4){0.f,0.f,0.f,0.f}; }
  float mr0 = -3.0e38f, mr1 = -3.0e38f, lr0 = 0.f, lr1 = 0.f;

  for (int tt = 0; tt < NTILE; ++tt) {
    const int cur = tt & 1, nxt = cur ^ 1;
    const bool hn = (tt + 1 < NTILE);
    f32x4 r[5]; int ma = 0; unsigned mb = 0;
    if (hn) {   // issue next-tile loads early (hide HBM latency under compute)
      if (ldr) {
        const float* src = encB + (size_t)((tt + 1) * STILE + lrow) * ND + ld0;
#pragma unroll
        for (int q = 0; q < 5; ++q) r[q] = *(const f32x4*)(src + 4 * q);
      }
      if (m32m) { if (tid >= 256 && tid < 320) ma = maskp[(size_t)b * NS + (tt + 1) * STILE + (tid - 256)]; }
      else      { if (tid >= 256 && tid < 272) mb = ((const unsigned*)maskp)[(((size_t)b * NS + (tt + 1) * STILE) >> 2) + (tid - 256)]; }
    }

    // ---- QK^T (swapped): D'[s][p] = E * Q^T, K = 96 (3-term bf16 split) ----
    const u16* ehR = eh + cur * 6656 + (16 * hq + l15) * 104;
    const u16* elR = el + cur * 6656 + (16 * hq + l15) * 104;
    bf16x8 ea[3], ec[3];
#pragma unroll
    for (int kk = 0; kk < 3; ++kk) {
      ea[kk] = *(const bf16x8*)&ehR[kk * 32 + g * 8];
      ec[kk] = *(const bf16x8*)&elR[kk * 32 + g * 8];
    }
    f32x4 a0 = (f32x4){0.f,0.f,0.f,0.f}, a1 = (f32x4){0.f,0.f,0.f,0.f};
#pragma unroll
    for (int kk = 0; kk < 3; ++kk) {
      a0 = mfma32(ea[kk], qb[0][kk], a0);
      a0 = mfma32(ec[kk], qb[0][kk], a0);
      a0 = mfma32(ea[kk], qlb[0][kk], a0);
      a1 = mfma32(ea[kk], qb[1][kk], a1);
      a1 = mfma32(ec[kk], qb[1][kk], a1);
      a1 = mfma32(ea[kk], qlb[1][kk], a1);
    }

    // ---- masked online softmax (rows = s, per-lane col = p) ----
    int mk[4];
#pragma unroll
    for (int rr = 0; rr < 4; ++rr) mk[rr] = mlds[cur * 64 + 16 * hq + 4 * g + rr];
    float sv0[4], sv1[4];
#pragma unroll
    for (int rr = 0; rr < 4; ++rr) {
      sv0[rr] = mk[rr] ? -3.0e38f : a0[rr];
      sv1[rr] = mk[rr] ? -3.0e38f : a1[rr];
    }
    float tm0 = fmaxf(fmaxf(sv0[0], sv0[1]), fmaxf(sv0[2], sv0[3]));
    tm0 = fmaxf(tm0, __shfl_xor(tm0, 16)); tm0 = fmaxf(tm0, __shfl_xor(tm0, 32));
    float tm1 = fmaxf(fmaxf(sv1[0], sv1[1]), fmaxf(sv1[2], sv1[3]));
    tm1 = fmaxf(tm1, __shfl_xor(tm1, 16)); tm1 = fmaxf(tm1, __shfl_xor(tm1, 32));
    float mn0 = fmaxf(mr0, tm0), mn1 = fmaxf(mr1, tm1);
    float esc0 = __expf(mr0 - mn0), esc1 = __expf(mr1 - mn1);
    float p0[4], p1[4];
#pragma unroll
    for (int rr = 0; rr < 4; ++rr) { p0[rr] = __expf(sv0[rr] - mn0); p1[rr] = __expf(sv1[rr] - mn1); }
    float u0 = p0[0] + p0[1] + p0[2] + p0[3];
    u0 += __shfl_xor(u0, 16); u0 += __shfl_xor(u0, 32);
    float u1 = p1[0] + p1[1] + p1[2] + p1[3];
    u1 += __shfl_xor(u1, 16); u1 += __shfl_xor(u1, 32);
    lr0 = lr0 * esc0 + u0; lr1 = lr1 * esc1 + u1;
    mr0 = mn0; mr1 = mn1;

    // rescale ctx (per-row factors broadcast from the lane owning that p)
    float fr0[4], fr1[4];
#pragma unroll
    for (int rr = 0; rr < 4; ++rr) {
      fr0[rr] = __shfl(esc0, 4 * g + rr);
      fr1[rr] = __shfl(esc1, 4 * g + rr);
    }
#pragma unroll
    for (int n = 0; n < 5; ++n) {
#pragma unroll
      for (int rr = 0; rr < 4; ++rr) { ctx0[n][rr] *= fr0[rr]; ctx1[n][rr] *= fr1[rr]; }
    }

    // ---- PV: ctx[p][d] += P[p][s16] * E[s16][d]; K=32 mfma, upper K-half zeroed ----
    union { unsigned u[4]; bf16x8 v; } PA0, PA1;
    PA0.u[0] = pack2r(p0[0], p0[1]); PA0.u[1] = pack2r(p0[2], p0[3]);
    PA0.u[2] = 0u; PA0.u[3] = 0u;
    PA1.u[0] = pack2r(p1[0], p1[1]); PA1.u[1] = pack2r(p1[2], p1[3]);
    PA1.u[2] = 0u; PA1.u[3] = 0u;
    const u16* eT = ehT + cur * 5760;
#pragma unroll
    for (int n = 0; n < 5; ++n) {
      const int dd = n * 16 + l15;
      s16x4 bf = *(const s16x4*)&eT[dd * 72 + ((((hq << 2) + g) ^ l15) << 2)];
      bf16x8 bb = { bf[0], bf[1], bf[2], bf[3], 0, 0, 0, 0 };
      ctx0[n] = mfma32(PA0.v, bb, ctx0[n]);
      ctx1[n] = mfma32(PA1.v, bb, ctx1[n]);
    }

    if (hn) { STAGE_WRITE(nxt); }
    __syncthreads();
  }

  // ---------- epilogue: merge 4 s-quarters, normalize, write ----------
  if (g == 0) {
    const int pb = (2 * mp) * 16 + l15;
    mst[hq * 64 + pb] = mr0;      lst[hq * 64 + pb] = lr0;
    mst[hq * 64 + pb + 16] = mr1; lst[hq * 64 + pb + 16] = lr1;
  }
  __syncthreads();
  float F0, F1;
  {
    const int p0i = (2 * mp) * 16 + l15, p1i = p0i + 16;
    float M0 = fmaxf(fmaxf(mst[p0i], mst[64 + p0i]), fmaxf(mst[128 + p0i], mst[192 + p0i]));
    float M1 = fmaxf(fmaxf(mst[p1i], mst[64 + p1i]), fmaxf(mst[128 + p1i], mst[192 + p1i]));
    F0 = __expf(mr0 - M0); F1 = __expf(mr1 - M1);
  }
  float g0[4], g1[4];
#pragma unroll
  for (int rr = 0; rr < 4; ++rr) { g0[rr] = __shfl(F0, 4 * g + rr); g1[rr] = __shfl(F1, 4 * g + rr); }
  float* cacc = (float*)smem;  // [64][84]
  for (int ph = 0; ph < 4; ++ph) {
    if (hq == ph) {
#pragma unroll
      for (int n = 0; n < 5; ++n) {
#pragma unroll
        for (int rr = 0; rr < 4; ++rr) {
          const int row0 = (2 * mp) * 16 + 4 * g + rr;
          const int col = n * 16 + l15;
          float v0 = ctx0[n][rr] * g0[rr];
          float v1 = ctx1[n][rr] * g1[rr];
          if (ph == 0) { cacc[row0 * 84 + col] = v0; cacc[(row0 + 16) * 84 + col] = v1; }
          else         { cacc[row0 * 84 + col] += v0; cacc[(row0 + 16) * 84 + col] += v1; }
        }
      }
    }
    __syncthreads();
  }
  {
    const int op = tid >> 3, oc = tid & 7, od0 = oc * 10;
    float Mv = fmaxf(fmaxf(mst[op], mst[64 + op]), fmaxf(mst[128 + op], mst[192 + op]));
    float Lv = lst[op] * __expf(mst[op] - Mv) + lst[64 + op] * __expf(mst[64 + op] - Mv)
             + lst[128 + op] * __expf(mst[128 + op] - Mv) + lst[192 + op] * __expf(mst[192 + op] - Mv);
    float inv = 1.0f / Lv;
    float* orow = out + ((size_t)b * NP + op) * ND;
#pragma unroll
    for (int i = 0; i < 10; i += 2) {
      float2 v;
      v.x = cacc[op * 84 + od0 + i] * inv;
      v.y = cacc[op * 84 + od0 + i + 1] * inv;
      *(float2*)&orow[od0 + i] = v;
    }
  }
}

extern "C" void kernel_launch(void* const* d_in, const int* in_sizes, int n_in,
                              void* d_out, int out_size, void* d_ws, size_t ws_size,
                              hipStream_t stream) {
  (void)in_sizes; (void)n_in; (void)out_size; (void)d_ws; (void)ws_size;
  const float* enc  = (const float*)d_in[0];
  const float* dec  = (const float*)d_in[1];
  const int*   mask = (const int*)d_in[2];
  const float* W    = (const float*)d_in[3];
  float* out = (float*)d_out;
  DecoderAttention_62989990363717_kernel<<<dim3(NB), dim3(NTHREADS), 0, stream>>>(
      enc, dec, mask, W, out);
}

// Round 4
// 63.440 us; speedup vs baseline: 1.2848x; 1.2848x over previous
//
#include <hip/hip_runtime.h>

#define NB 256
#define NS 2048
#define NP 64
#define ND 80
#define STILE 64
#define NTILE 32            // NS/STILE
#define NTHREADS 1024

typedef __attribute__((ext_vector_type(4))) float f32x4;
typedef __attribute__((ext_vector_type(8))) short bf16x8;
typedef __attribute__((ext_vector_type(4))) short s16x4;
typedef unsigned short u16;

// ---------------- LDS layout (bytes) ----------------
// eh   u16[2][64][104] @ 0      (26624)  bf16-RNE of enc [s][d], K-pad 80..95 zeroed once
// el   u16[2][64][104] @ 26624  (26624)  bf16 residual
// ehT  u16[2][80][72]  @ 53248  (23040)  transposed hi copy [d][slot], slot=(s+12*(d>>3))&63
// mfull int[2048]      @ 76288  (8192)   whole mask row, loaded once in prologue
// mst  f32[4][64]      @ 84480  (1024);  lst @ 85504 (1024);  modep @ 86528
// prologue overlay: W f32[80][84]@0 ; dec f32[64][84]@26880 ; qtmp f32[64][100]@0
// epilogue overlay: cacc f32[64][84]@0
#define SMEM_BYTES 86592

__device__ __forceinline__ float bft(float f) {
  return __uint_as_float(__float_as_uint(f) & 0xFFFF0000u);
}
__device__ __forceinline__ u16 h16(float f) { return (u16)(__float_as_uint(f) >> 16); }
__device__ __forceinline__ u16 h16r(float f) {  // round-to-nearest-even bf16
  unsigned u = __float_as_uint(f);
  u += 0x7FFFu + ((u >> 16) & 1u);
  return (u16)(u >> 16);
}
__device__ __forceinline__ unsigned pack2r(float lo, float hi) {
  return (unsigned)h16r(lo) | ((unsigned)h16r(hi) << 16);
}

// 16x16 K=32 bf16 MFMA. C/D: col=lane&15, row=4*(lane>>4)+r [guide m89/m91].
// A and B share the (lane-group, reg-slot)->k map, so identical slot placement
// on both sides contracts correctly regardless of internal k permutation.
__device__ __forceinline__ f32x4 mfma32(bf16x8 a, bf16x8 b, f32x4 c) {
  return __builtin_amdgcn_mfma_f32_16x16x32_bf16(a, b, c, 0, 0, 0);
}

__global__ __launch_bounds__(NTHREADS, 4)
void DecoderAttention_62989990363717_kernel(const float* __restrict__ enc,
                                            const float* __restrict__ dec,
                                            const int* __restrict__ maskp,
                                            const float* __restrict__ W,
                                            float* __restrict__ out)
{
  __shared__ __align__(16) char smem[SMEM_BYTES];

  u16* eh    = (u16*)smem;                // [2][64][104]
  u16* el    = (u16*)(smem + 26624);
  u16* ehT   = (u16*)(smem + 53248);      // [2][80][72]
  int* mfull = (int*)(smem + 76288);      // [2048]
  float* mst = (float*)(smem + 84480);    // [4][64]
  float* lst = (float*)(smem + 85504);    // [4][64]
  int* modep = (int*)(smem + 86528);

  const int tid  = (int)threadIdx.x;
  const int lane = tid & 63;
  const int wv   = tid >> 6;    // 0..15
  const int pp   = wv & 3;      // p-block: rows [16*pp, 16*pp+16)
  const int hq   = wv >> 2;     // s-quarter within tile: [16*hq, 16*hq+16)
  const int l15  = lane & 15;
  const int g    = lane >> 4;
  const int b    = (int)blockIdx.x;

  const float* encB = enc + (size_t)b * NS * ND;
  const float* decB = dec + (size_t)b * NP * ND;

  // ---------- prologue: W, dec -> LDS; mask-mode; full mask preload; Q ----------
  {
    float* Wl = (float*)smem;            // [80][84]
    float* dl = (float*)(smem + 26880);  // [64][84]
    for (int i = tid; i < 80 * 80; i += NTHREADS) Wl[(i / 80) * 84 + (i % 80)] = W[i];
    for (int i = tid; i < 64 * 80; i += NTHREADS) dl[(i / 80) * 84 + (i % 80)] = decB[i];
    if (tid == 0) {
      const unsigned* mw = (const unsigned*)maskp;
      int ok = 1;
      for (int i = 0; i < 16; ++i) ok &= (mw[i] <= 1u);
      *modep = ok;   // 1 => int32 mask, 0 => int8 mask
    }
    __syncthreads();
    const int m32 = *modep;
    if (m32) {
      mfull[tid]        = maskp[(size_t)b * NS + tid];
      mfull[tid + 1024] = maskp[(size_t)b * NS + tid + 1024];
    } else if (tid < 512) {
      unsigned w = ((const unsigned*)maskp)[(size_t)b * (NS / 4) + tid];
      int4 mm = make_int4((int)(w & 255u), (int)((w >> 8) & 255u),
                          (int)((w >> 16) & 255u), (int)(w >> 24));
      *(int4*)&mfull[4 * tid] = mm;
    }
    // Q = dec @ W^T in fp32 (512 threads: p = tid&63, e-range = 10*qw)
    float qa[10];
    const int qp = tid & 63, qw = (tid >> 6) & 7;
    if (tid < 512) {
#pragma unroll
      for (int j = 0; j < 10; ++j) qa[j] = 0.f;
      for (int kg = 0; kg < 20; ++kg) {
        f32x4 dv = *(const f32x4*)&dl[qp * 84 + kg * 4];
#pragma unroll
        for (int j = 0; j < 10; ++j) {
          f32x4 wv4 = *(const f32x4*)&Wl[(qw * 10 + j) * 84 + kg * 4];
          qa[j] = fmaf(dv.x, wv4.x, qa[j]);
          qa[j] = fmaf(dv.y, wv4.y, qa[j]);
          qa[j] = fmaf(dv.z, wv4.z, qa[j]);
          qa[j] = fmaf(dv.w, wv4.w, qa[j]);
        }
      }
    }
    __syncthreads();            // Wl/dl reads done
    float* qtmp = (float*)smem; // [64][100], zeros at d=80..95
    if (tid < 512) {
#pragma unroll
      for (int j = 0; j < 10; ++j) qtmp[qp * 100 + qw * 10 + j] = qa[j];
      if (qw == 7) {
#pragma unroll
        for (int z = 0; z < 16; ++z) qtmp[qp * 100 + 80 + z] = 0.f;
      }
    }
    __syncthreads();
  }

  // ---------- Q fragments (persistent, bf16 hi/lo split) ----------
  bf16x8 qb[3], qlb[3];
  {
    const float* qtmp = (const float*)smem;
    const int prow = 16 * pp + l15;
#pragma unroll
    for (int kk = 0; kk < 3; ++kk) {
      const int d0 = kk * 32 + g * 8;
      f32x4 f0 = *(const f32x4*)&qtmp[prow * 100 + d0];
      f32x4 f1 = *(const f32x4*)&qtmp[prow * 100 + d0 + 4];
      float fq[8] = {f0.x, f0.y, f0.z, f0.w, f1.x, f1.y, f1.z, f1.w};
      union { u16 u[8]; bf16x8 v; } H, L;
#pragma unroll
      for (int j = 0; j < 8; ++j) {
        H.u[j] = h16(fq[j]);
        L.u[j] = h16(fq[j] - bft(fq[j]));
      }
      qb[kk] = H.v; qlb[kk] = L.v;
    }
  }
  __syncthreads();   // qtmp dead; staging may overwrite

  // ---------- zero K-pad (d=80..95) once, both buffers ----------
  if (tid < 256) {
    const int arr = tid >> 7, buf = (tid >> 6) & 1, s = tid & 63;
    u16* p = (arr ? el : eh) + buf * 6656 + s * 104 + 80;
    *(uint4*)p = make_uint4(0u, 0u, 0u, 0u);
    *(uint4*)(p + 8) = make_uint4(0u, 0u, 0u, 0u);
  }

  // loader roles: tid<640 stage enc (10 threads/row, 8 f32 each)
  const bool ldr = (tid < 640);
  const int srow = tid / 10;
  const int th   = tid - srow * 10;
  u16* ehW = eh + srow * 104 + th * 8;
  u16* elW = el + srow * 104 + th * 8;
  const int tslot = (srow + 12 * th) & 63;   // slot(s,d) = (s + 12*(d>>3)) & 63
  const float* gsrc = encB + srow * ND + th * 8;

#define STAGE_WRITE(bi)                                                          \
  do {                                                                           \
    if (ldr) {                                                                   \
      float fv[8] = {r0.x, r0.y, r0.z, r0.w, r1.x, r1.y, r1.z, r1.w};            \
      unsigned hh[4], ll[4];                                                     \
      _Pragma("unroll")                                                          \
      for (int q = 0; q < 4; ++q) {                                              \
        float flo = fv[2*q], fhi = fv[2*q+1];                                    \
        unsigned h = pack2r(flo, fhi);                                           \
        hh[q] = h;                                                               \
        float rlo = flo - __uint_as_float(h << 16);                              \
        float rhi = fhi - __uint_as_float(h & 0xFFFF0000u);                      \
        ll[q] = pack2r(rlo, rhi);                                                \
      }                                                                          \
      *(uint4*)(ehW + (bi) * 6656) = make_uint4(hh[0], hh[1], hh[2], hh[3]);     \
      *(uint4*)(elW + (bi) * 6656) = make_uint4(ll[0], ll[1], ll[2], ll[3]);     \
      u16* eT_ = ehT + (bi) * 5760 + (8 * th) * 72 + tslot;                      \
      _Pragma("unroll")                                                          \
      for (int i2 = 0; i2 < 8; ++i2) {                                           \
        eT_[i2 * 72] = (u16)(hh[i2 >> 1] >> ((i2 & 1) * 16));                    \
      }                                                                          \
    }                                                                            \
  } while (0)

  // ---------- stage tile 0 ----------
  {
    f32x4 r0, r1;
    if (ldr) { r0 = *(const f32x4*)gsrc; r1 = *(const f32x4*)(gsrc + 4); }
    STAGE_WRITE(0);
    __syncthreads();
  }

  // ---------- main loop ----------
  f32x4 ctx[5];
#pragma unroll
  for (int n = 0; n < 5; ++n) ctx[n] = (f32x4){0.f, 0.f, 0.f, 0.f};
  float mr = -3.0e38f, lr = 0.f;
  const int pvB = 4 * (4 * hq + g) + 12 * (l15 >> 3);

  for (int tt = 0; tt < NTILE; ++tt) {
    const int cur = tt & 1, nxt = cur ^ 1;
    const bool hn = (tt + 1 < NTILE);
    f32x4 r0, r1;
    if (hn && ldr) {   // issue next-tile loads early (hide HBM latency)
      const float* src = gsrc + (size_t)(tt + 1) * STILE * ND;
      r0 = *(const f32x4*)src; r1 = *(const f32x4*)(src + 4);
    }

    // ---- QK^T (swapped): D'[s][p] = E * Q^T, K=96, 3-term bf16 split ----
    const u16* ehR = eh + cur * 6656 + (16 * hq + l15) * 104;
    const u16* elR = el + cur * 6656 + (16 * hq + l15) * 104;
    bf16x8 ea[3], ec[3];
#pragma unroll
    for (int kk = 0; kk < 3; ++kk) {
      ea[kk] = *(const bf16x8*)&ehR[kk * 32 + g * 8];
      ec[kk] = *(const bf16x8*)&elR[kk * 32 + g * 8];
    }
    f32x4 a = (f32x4){0.f, 0.f, 0.f, 0.f};
#pragma unroll
    for (int kk = 0; kk < 3; ++kk) {
      a = mfma32(ea[kk], qb[kk], a);
      a = mfma32(ec[kk], qb[kk], a);
      a = mfma32(ea[kk], qlb[kk], a);
    }

    // ---- masked online softmax (rows = s, per-lane col = p), defer-max ----
    int4 mki = *(const int4*)&mfull[tt * 64 + 16 * hq + 4 * g];
    float sv[4];
    sv[0] = mki.x ? -3.0e38f : a[0];
    sv[1] = mki.y ? -3.0e38f : a[1];
    sv[2] = mki.z ? -3.0e38f : a[2];
    sv[3] = mki.w ? -3.0e38f : a[3];
    float tm = fmaxf(fmaxf(sv[0], sv[1]), fmaxf(sv[2], sv[3]));
    tm = fmaxf(tm, __shfl_xor(tm, 16));
    tm = fmaxf(tm, __shfl_xor(tm, 32));
    const bool need = !__all(tm <= mr + 8.0f);
    if (need) {
      float mn = fmaxf(mr, tm);
      float esc = __expf(mr - mn);
      lr *= esc; mr = mn;
      float fr[4];
#pragma unroll
      for (int rr = 0; rr < 4; ++rr) fr[rr] = __shfl(esc, 4 * g + rr);
#pragma unroll
      for (int n = 0; n < 5; ++n) {
#pragma unroll
        for (int rr = 0; rr < 4; ++rr) ctx[n][rr] *= fr[rr];
      }
    }
    float p[4];
#pragma unroll
    for (int rr = 0; rr < 4; ++rr) p[rr] = __expf(sv[rr] - mr);
    float u = p[0] + p[1] + p[2] + p[3];
    u += __shfl_xor(u, 16); u += __shfl_xor(u, 32);
    lr += u;

    // ---- PV: ctx[p][d] += P[p][s16] * E[s16][d]; B from permuted-slot ehT ----
    union { unsigned uu[4]; bf16x8 v; } PA;
    PA.uu[0] = pack2r(p[0], p[1]); PA.uu[1] = pack2r(p[2], p[3]);
    PA.uu[2] = 0u; PA.uu[3] = 0u;
    const u16* eT = ehT + cur * 5760;
#pragma unroll
    for (int n = 0; n < 5; ++n) {
      const int dd = 16 * n + l15;
      s16x4 bf = *(const s16x4*)&eT[dd * 72 + ((pvB + 24 * n) & 63)];
      bf16x8 bb = {bf[0], bf[1], bf[2], bf[3], 0, 0, 0, 0};
      ctx[n] = mfma32(PA.v, bb, ctx[n]);
    }

    if (hn) { STAGE_WRITE(nxt); }
    __syncthreads();
  }

  // ---------- epilogue: merge 4 s-quarters, normalize, write ----------
  if (g == 0) {
    mst[hq * 64 + 16 * pp + l15] = mr;
    lst[hq * 64 + 16 * pp + l15] = lr;
  }
  __syncthreads();
  float F;
  {
    const int pi = 16 * pp + l15;
    float M = fmaxf(fmaxf(mst[pi], mst[64 + pi]), fmaxf(mst[128 + pi], mst[192 + pi]));
    F = __expf(mr - M);
  }
  float gg[4];
#pragma unroll
  for (int rr = 0; rr < 4; ++rr) gg[rr] = __shfl(F, 4 * g + rr);
  float* cacc = (float*)smem;  // [64][84]
  for (int ph = 0; ph < 4; ++ph) {
    if (hq == ph) {
#pragma unroll
      for (int n = 0; n < 5; ++n) {
#pragma unroll
        for (int rr = 0; rr < 4; ++rr) {
          const int row = 16 * pp + 4 * g + rr;
          const int col = 16 * n + l15;
          float v = ctx[n][rr] * gg[rr];
          if (ph == 0) cacc[row * 84 + col] = v;
          else         cacc[row * 84 + col] += v;
        }
      }
    }
    __syncthreads();
  }
  {
    const int op = tid >> 4, oc = tid & 15;
    float Mv = fmaxf(fmaxf(mst[op], mst[64 + op]), fmaxf(mst[128 + op], mst[192 + op]));
    float Lv = lst[op] * __expf(mst[op] - Mv) + lst[64 + op] * __expf(mst[64 + op] - Mv)
             + lst[128 + op] * __expf(mst[128 + op] - Mv) + lst[192 + op] * __expf(mst[192 + op] - Mv);
    float inv = 1.0f / Lv;
    float* orow = out + ((size_t)b * NP + op) * ND + oc * 5;
    const float* crow = cacc + op * 84 + oc * 5;
#pragma unroll
    for (int i = 0; i < 5; ++i) orow[i] = crow[i] * inv;
  }
}

extern "C" void kernel_launch(void* const* d_in, const int* in_sizes, int n_in,
                              void* d_out, int out_size, void* d_ws, size_t ws_size,
                              hipStream_t stream) {
  (void)in_sizes; (void)n_in; (void)out_size; (void)d_ws; (void)ws_size;
  const float* enc  = (const float*)d_in[0];
  const float* dec  = (const float*)d_in[1];
  const int*   mask = (const int*)d_in[2];
  const float* W    = (const float*)d_in[3];
  float* out = (float*)d_out;
  DecoderAttention_62989990363717_kernel<<<dim3(NB), dim3(NTHREADS), 0, stream>>>(
      enc, dec, mask, W, out);
}